// Round 3
// baseline (137.743 us; speedup 1.0000x reference)
//
#include <hip/hip_runtime.h>

// StericClashConstraint: N=16384 pts [N,3] fp32.
// out[0..3N-1] = pos passthrough; out[3N] = mean(max(1-dist,0), diag=0) * 0.02
//
// Round 9: Z-SORT PRUNING. Counters show pure-VALU-bound O(N^2) loop (HBM 0.24%,
// 0 bank conflicts); only ~113k/134e6 pairs violate. z ~ N(0,5) => P(|dz|<1)=0.11.
// Counting-sort points by z into 512 bins of width 1/8 ([-32,32), clamped ends),
// then i-group g (512 consecutive sorted pts) only scans j in [gstart+1, jend_g)
// where jend_g = binStart[cellmax_g + 10]. Excluded pairs: dz >= 9/8 - 8e-6 > 1
// (fp-rounding-proof margin) => violation EXACTLY 0 in both ref and kernel.
// Included pairs: identical branchless math as R8 => no numerics drift.
// Pair-slots 151e6 -> ~27e6 (5.5x). Sum is order-independent: scatter
// {x,y,z,|p|^2}, never track the permutation.
// Pipeline: memset(hdr) -> prep(passthrough+hist) -> scan(1 blk) -> scatter -> pair.
// Pair: 32 groups x 64 QB-aligned disjoint j-segments = 2048 blocks, 8/CU.

constexpr int   N     = 16384;
constexpr int   BLOCK = 256;            // 4 waves
constexpr int   GSZ   = 512;            // i-group size
constexpr int   IPT   = GSZ / BLOCK;    // 2 i's per thread
constexpr int   NG    = N / GSZ;        // 32 i-groups
constexpr int   F     = 64;             // j-segments per group
constexpr int   NB    = NG * F;         // 2048 blocks = 8/CU
constexpr int   QB    = 4;              // j's prefetched per batch
constexpr int   JPAD  = 8;              // sentinel pad: prefetch never reads OOB
constexpr int   NBINS = 512;            // z-bins, width 1/8, covering [-32,32)
constexpr float BINW_INV = 8.0f;
constexpr int   MARGIN = 10;            // cell_j >= cellmax+10 => dz > 1 guaranteed

__device__ __forceinline__ int zcell(float z) {
    int c = (int)floorf(z * BINW_INV) + NBINS / 2;
    return min(max(c, 0), NBINS - 1);
}

// ---- k1: passthrough + z-histogram -----------------------------------------
__global__ void prep_kernel(const float* __restrict__ pos, float* __restrict__ out,
                            unsigned int* __restrict__ hist) {
    const int t = blockIdx.x * blockDim.x + threadIdx.x;   // 0..16383
    if (t < (N * 3) / 4) {
        reinterpret_cast<float4*>(out)[t] = reinterpret_cast<const float4*>(pos)[t];
    }
    const float z = pos[3 * t + 2];
    atomicAdd(&hist[zcell(z)], 1u);
}

// ---- k2: exclusive prefix sum over 512 bins (1 block) ----------------------
__global__ void scan_kernel(const unsigned int* __restrict__ hist,
                            int* __restrict__ binStart, unsigned int* __restrict__ cursor) {
    __shared__ int sm[NBINS];
    const int t = threadIdx.x;
    const int v = (int)hist[t];
    sm[t] = v;
    __syncthreads();
    for (int off = 1; off < NBINS; off <<= 1) {
        const int a = (t >= off) ? sm[t - off] : 0;
        __syncthreads();
        sm[t] += a;
        __syncthreads();
    }
    const int excl = sm[t] - v;
    binStart[t] = excl;
    cursor[t]   = (unsigned int)excl;
}

// ---- k3: scatter into z-sorted {x,y,z,|p|^2} array -------------------------
__global__ void scatter_kernel(const float* __restrict__ pos,
                               unsigned int* __restrict__ cursor,
                               float4* __restrict__ jt4s) {
    const int t = blockIdx.x * blockDim.x + threadIdx.x;   // 0..16383
    const float x = pos[3 * t], y = pos[3 * t + 1], z = pos[3 * t + 2];
    const unsigned int dst = atomicAdd(&cursor[zcell(z)], 1u);
    jt4s[dst] = make_float4(x, y, z, fmaf(x, x, fmaf(y, y, z * z)));
    if (t < JPAD) {
        // far sentinel: d2 astronomically positive -> w << 0 -> clamped to 0
        jt4s[N + t] = make_float4(0.0f, 0.0f, 1.0e6f, 4.0e12f);
    }
}

// ---- k4: pruned pair sweep -------------------------------------------------
template <bool MASKED>
__device__ __forceinline__ float cols(const float4* __restrict__ jt,
                                      int j0, int len, int i0,
                                      const float (&xi2)[IPT], const float (&yi2)[IPT],
                                      const float (&zi2)[IPT], const float (&sqi)[IPT]) {
    float s = 0.0f;
    if (len <= 0) return s;
    const int nfull = len & ~(QB - 1);
    float4 cur[QB];
    #pragma unroll
    for (int u = 0; u < QB; ++u) cur[u] = jt[j0 + u];          // pad makes safe
    for (int qb = 0; qb < nfull; qb += QB) {
        float4 nxt[QB];
        #pragma unroll
        for (int u = 0; u < QB; ++u) nxt[u] = jt[j0 + qb + QB + u];
        #pragma unroll
        for (int u = 0; u < QB; ++u) {
            const float4 pj = cur[u];
            const int jq = j0 + qb + u;
            #pragma unroll
            for (int k = 0; k < IPT; ++k) {
                float d = fmaf(xi2[k], pj.x, pj.w);
                d = fmaf(yi2[k], pj.y, d);
                d = fmaf(zi2[k], pj.z, d);                     // sq_j - 2*dot
                const float d2 = fmaxf(d + sqi[k], 0.0f);      // + sq_i, clamp
                float w = 1.0f - __builtin_amdgcn_sqrtf(d2);   // 1 - dist
                w = fmaxf(w, 0.0f);                            // clamp(min=0)
                if (MASKED) w = (jq > i0 + k * BLOCK) ? w : 0.0f;   // j>i only
                s += w;
            }
        }
        #pragma unroll
        for (int u = 0; u < QB; ++u) cur[u] = nxt[u];
    }
    // tail (<= QB-1 j's); cur[] already holds jt[j0+nfull .. +QB-1]
    #pragma unroll
    for (int u = 0; u < QB - 1; ++u) {
        if (nfull + u < len) {                                 // uniform branch
            const float4 pj = cur[u];
            const int jq = j0 + nfull + u;
            #pragma unroll
            for (int k = 0; k < IPT; ++k) {
                float d = fmaf(xi2[k], pj.x, pj.w);
                d = fmaf(yi2[k], pj.y, d);
                d = fmaf(zi2[k], pj.z, d);
                const float d2 = fmaxf(d + sqi[k], 0.0f);
                float w = 1.0f - __builtin_amdgcn_sqrtf(d2);
                w = fmaxf(w, 0.0f);
                if (MASKED) w = (jq > i0 + k * BLOCK) ? w : 0.0f;
                s += w;
            }
        }
    }
    return s;
}

__global__ void __launch_bounds__(BLOCK, 8)
pair_kernel(const float4* __restrict__ jt4s, const int* __restrict__ binStart,
            float* __restrict__ out, float* __restrict__ acc,
            unsigned int* __restrict__ cnt) {
    __shared__ float wsum[BLOCK / 64];
    const int b = blockIdx.x;
    const int t = threadIdx.x;
    const int g = b / F, f = b % F;          // F=64: shifts
    const int gstart = g * GSZ;

    // group j-window (uniform): last sorted point has the max cell of the group
    const float lastz = jt4s[gstart + GSZ - 1].z;
    const int cellmax = zcell(lastz);
    const int jidx = cellmax + MARGIN;
    const int jend = (jidx >= NBINS) ? N : binStart[jidx];
    const int jbeg = gstart + 1;
    const int jlen = jend - jbeg;            // >= GSZ-1 always
    const int seg  = (((jlen + F - 1) / F) + QB - 1) & ~(QB - 1);  // QB-aligned
    const int j0   = jbeg + f * seg;
    const int j1   = min(j0 + seg, jend);
    const int len  = j1 - j0;                // may be <=0 for tail blocks

    float s = 0.0f;
    if (len > 0) {
        const int i0 = gstart + t;
        float xi2[IPT], yi2[IPT], zi2[IPT], sqi[IPT];
        #pragma unroll
        for (int k = 0; k < IPT; ++k) {
            const float4 w = jt4s[i0 + k * BLOCK];
            xi2[k] = -2.0f * w.x;
            yi2[k] = -2.0f * w.y;
            zi2[k] = -2.0f * w.z;
            sqi[k] = w.w;
        }
        if (j0 < gstart + GSZ)   // segment overlaps own group: need j>i mask
            s = cols<true >(jt4s, j0, len, i0, xi2, yi2, zi2, sqi);
        else
            s = cols<false>(jt4s, j0, len, i0, xi2, yi2, zi2, sqi);
    }

    // reduce: wave shuffle -> LDS -> one atomic per block
    for (int off = 32; off > 0; off >>= 1) s += __shfl_down(s, off);
    if ((t & 63) == 0) wsum[t >> 6] = s;
    __syncthreads();
    if (t == 0) {
        float bs = 0.0f;
        #pragma unroll
        for (int w = 0; w < BLOCK / 64; ++w) bs += wsum[w];
        atomicAdd(acc, bs);
        __threadfence();
        const unsigned int done = atomicAdd(cnt, 1u);
        if (done == (unsigned int)(NB - 1)) {          // last block finalizes
            __threadfence();
            const float total = atomicAdd(acc, 0.0f);  // device-coherent read
            const double mean = 2.0 * (double)total / ((double)N * (double)N);
            out[(size_t)N * 3] = (float)(mean * 0.02);
        }
    }
}

extern "C" void kernel_launch(void* const* d_in, const int* in_sizes, int n_in,
                              void* d_out, int out_size, void* d_ws, size_t ws_size,
                              hipStream_t stream) {
    const float* pos = (const float*)d_in[0];
    float* out = (float*)d_out;
    // ws layout:
    //   0:    acc (float)        4: cnt (uint)
    //   16:   hist[512]  (2048 B)
    //   2064: binStart[512] (2048 B)
    //   4112: cursor[512]  (2048 B)
    //   8192: jt4s[(N+JPAD) x float4]  (~256 KiB)
    float*        acc      = (float*)d_ws;
    unsigned int* cnt      = (unsigned int*)d_ws + 1;
    unsigned int* hist     = (unsigned int*)((char*)d_ws + 16);
    int*          binStart = (int*)((char*)d_ws + 2064);
    unsigned int* cursor   = (unsigned int*)((char*)d_ws + 4112);
    float4*       jt4s     = (float4*)((char*)d_ws + 8192);

    hipMemsetAsync(d_ws, 0, 2064, stream);   // acc, cnt, hist = 0

    prep_kernel   <<<N / 256, 256, 0, stream>>>(pos, out, hist);
    scan_kernel   <<<1, NBINS, 0, stream>>>(hist, binStart, cursor);
    scatter_kernel<<<N / 256, 256, 0, stream>>>(pos, cursor, jt4s);
    pair_kernel   <<<NB, BLOCK, 0, stream>>>(jt4s, binStart, out, acc, cnt);
}